// Round 1
// 466.440 us; speedup vs baseline: 1.5424x; 1.5424x over previous
//
#include <hip/hip_runtime.h>
#include <hip/hip_bf16.h>

typedef __hip_bfloat16 bf16;
typedef short bf16x4v __attribute__((ext_vector_type(4)));
typedef short bf16x8v __attribute__((ext_vector_type(8)));
typedef float f32x4v __attribute__((ext_vector_type(4)));

union U8 { bf16 h[8]; bf16x8v v; };
union U4 { bf16 h[4]; bf16x4v v; };

#define MFMA(a, b, c) __builtin_amdgcn_mfma_f32_16x16x32_bf16((a), (b), (c), 0, 0, 0)

#define GLOAD_LDS16(gp, lp)                                         \
  __builtin_amdgcn_global_load_lds(                                 \
      (const __attribute__((address_space(1))) void*)(gp),          \
      (__attribute__((address_space(3))) void*)(lp), 16, 0, 0)
#define WAIT_VMCNT_2 asm volatile("s_waitcnt vmcnt(2)" ::: "memory")
#define WAIT_VMCNT_0 asm volatile("s_waitcnt vmcnt(0)" ::: "memory")
#define WAIT_LGKM_0 asm volatile("s_waitcnt lgkmcnt(0)" ::: "memory")
#define BARRIER __builtin_amdgcn_s_barrier()

// ---------------------------------------------------------------------------
// K0: transpose + f32->bf16 convert the four 512x512 weight matrices into
// [n][k] layout so MFMA B-fragments are contiguous 16B reads. WT=[4][512][512].
// ---------------------------------------------------------------------------
__global__ __launch_bounds__(1024) void conv_weights(
    const float* __restrict__ Wq, const float* __restrict__ Wk,
    const float* __restrict__ Wv, const float* __restrict__ Wp,
    bf16* __restrict__ WT) {
  __shared__ float t[32][33];
  const float* srcs[4] = {Wq, Wk, Wv, Wp};
  const float* src = srcs[blockIdx.z];
  int k0 = blockIdx.y * 32, n0 = blockIdx.x * 32;
  t[threadIdx.y][threadIdx.x] = src[(size_t)(k0 + threadIdx.y) * 512 + n0 + threadIdx.x];
  __syncthreads();
  WT[((size_t)blockIdx.z * 512 + n0 + threadIdx.y) * 512 + k0 + threadIdx.x] =
      (bf16)t[threadIdx.x][threadIdx.y];
}

// ---------------------------------------------------------------------------
// K0b: convert X (8*2048*512 f32) to canonical bf16 (parked in the Y region
// of d_out; consumed by qkv_gemm before proj_ln overwrites Y).
// ---------------------------------------------------------------------------
__global__ __launch_bounds__(256) void conv_x(const float* __restrict__ x,
                                              bf16* __restrict__ Xb) {
  size_t base = ((size_t)blockIdx.x * 256 + threadIdx.x) * 8;
  f32x4v a = *(const f32x4v*)(x + base);
  f32x4v b = *(const f32x4v*)(x + base + 4);
  U8 u;
#pragma unroll
  for (int e = 0; e < 4; e++) {
    u.h[e] = (bf16)a[e];
    u.h[4 + e] = (bf16)b[e];
  }
  *(bf16x8v*)(Xb + base) = u.v;
}

// ---------------------------------------------------------------------------
// K1: QKV projection GEMM. OUT[m][n] = sum_k Xb[m][k]*WT[n][k] + bias[n].
// 128x128 tile, BK=32, 256 threads (4 waves, 2x2 of 64x64).
// blockIdx.z selects Q / K / V.
// V is written FRAGMENT-PACKED for the attention PV phase:
//   Vf elem idx = (((b*32 + n>>4)*64 + s>>5)*4 + (s>>3)&3)*128 + (n&15)*8 + (s&7)
// so a PV B-fragment (n-tile, 32-s-slice) is one contiguous 1KB block
// (lane*16B). Written as 8-B packed stores (4 consecutive s per lane).
// ---------------------------------------------------------------------------
__global__ __launch_bounds__(256) void qkv_gemm(
    const bf16* __restrict__ Xb, const bf16* __restrict__ WTall,
    const float* __restrict__ bq, const float* __restrict__ bk,
    const float* __restrict__ bv,
    bf16* __restrict__ Q, bf16* __restrict__ Km, bf16* __restrict__ Vf) {
  const int which = blockIdx.z;
  const bf16* Wt = WTall + (size_t)which * 512 * 512;
  const float* bias = (which == 0) ? bq : (which == 1 ? bk : bv);
  const int n0 = blockIdx.x * 128;
  const int m0 = blockIdx.y * 128;
  __shared__ bf16 As[128][40];
  __shared__ bf16 Bs[128][40];
  const int tid = threadIdx.x;
  const int lane = tid & 63, w = tid >> 6;
  const int wr = w >> 1, wc = w & 1;
  const int quad = lane >> 4, l15 = lane & 15;

  f32x4v acc[4][4];
#pragma unroll
  for (int i = 0; i < 4; i++)
#pragma unroll
    for (int j = 0; j < 4; j++) acc[i][j] = (f32x4v){0.f, 0.f, 0.f, 0.f};

  const int srow = tid >> 2, scol = (tid & 3) * 8;
  for (int kt = 0; kt < 16; ++kt) {
    const int k0 = kt * 32;
#pragma unroll
    for (int it = 0; it < 2; ++it) {
      int r = srow + it * 64;
      *(bf16x8v*)&As[r][scol] = *(const bf16x8v*)&Xb[(size_t)(m0 + r) * 512 + k0 + scol];
      *(bf16x8v*)&Bs[r][scol] = *(const bf16x8v*)&Wt[(size_t)(n0 + r) * 512 + k0 + scol];
    }
    __syncthreads();
    bf16x8v a[4], b[4];
#pragma unroll
    for (int i = 0; i < 4; i++) a[i] = *(const bf16x8v*)&As[wr * 64 + i * 16 + l15][quad * 8];
#pragma unroll
    for (int j = 0; j < 4; j++) b[j] = *(const bf16x8v*)&Bs[wc * 64 + j * 16 + l15][quad * 8];
#pragma unroll
    for (int i = 0; i < 4; i++)
#pragma unroll
      for (int j = 0; j < 4; j++) acc[i][j] = MFMA(a[i], b[j], acc[i][j]);
    __syncthreads();
  }

#pragma unroll
  for (int j = 0; j < 4; j++) {
    int col = n0 + wc * 64 + j * 16 + l15;
    float bv_ = bias[col];
#pragma unroll
    for (int i = 0; i < 4; i++) {
      if (which == 2) {
        int row0 = m0 + wr * 64 + i * 16 + quad * 4;  // s for r=0; r adds +1..3
        int b_ = row0 >> 11, s_ = row0 & 2047;
        size_t fi = ((((size_t)b_ * 32 + (col >> 4)) * 64 + (s_ >> 5)) * 4 +
                     ((s_ >> 3) & 3)) * 128 +
                    (size_t)(col & 15) * 8 + (s_ & 7);
        U4 p4;
#pragma unroll
        for (int r = 0; r < 4; r++) p4.h[r] = (bf16)(acc[i][j][r] + bv_);
        *(bf16x4v*)(Vf + fi) = p4.v;  // 8-B aligned (s_&7 in {0,4})
      } else {
#pragma unroll
        for (int r = 0; r < 4; r++) {
          int row = m0 + wr * 64 + i * 16 + quad * 4 + r;
          float v = acc[i][j][r] + bv_;
          if (which == 0) Q[(size_t)row * 512 + col] = (bf16)v;
          else            Km[(size_t)row * 512 + col] = (bf16)v;
        }
      }
    }
  }
}

// ---------------------------------------------------------------------------
// K-chunk staging for attn phase 1: chunk c = (stile = c&31, dc = c>>5) is
// K[stile*64 .. +64][dc*128 .. +128] = 16 KB, staged via global_load_lds into
// a 3-slot LDS ring. LDS dest is linear (wave-uniform base + lane*16); the
// XOR bank-swizzle (byte ^= (row&7)<<4, 256-B rows) is applied by permuting
// the per-lane GLOBAL source segment (rule: both-sides-or-neither).
// ---------------------------------------------------------------------------
__device__ __forceinline__ void stage_k(const bf16* __restrict__ Kb, char* kring,
                                        int c, int slot, int w, int lane) {
  const int stile = c & 31, dc = c >> 5;
  const bf16* gb = Kb + (size_t)stile * (64 * 512) + dc * 128;
  char* lb = kring + slot * 16384 + w * 2048;
#pragma unroll
  for (int i = 0; i < 2; i++) {
    const int R = (w * 2 + i) * 4 + (lane >> 4);      // row within 64-row tile
    const int segp = (lane & 15) ^ (R & 7);           // pre-swizzled 16B segment
    GLOAD_LDS16(gb + (size_t)R * 512 + segp * 8, lb + i * 1024);
  }
}

// ---------------------------------------------------------------------------
// K2 v3: fused attention. One block = one (batch, 32-row Q-tile), 512 thr.
// Batch = blockIdx.x & 7 (XCD-pinned K/V in that XCD's L2).
// Wave w = (rg = w>>2, cgi = w&3): rows rg*16.., cols cgi*16 within each
// 64-col s-tile; acc[32 s-tiles] covers all 2048 S columns.
// Phase 1: K staged cooperatively through a 3-slot LDS ring
//          (global_load_lds, swizzled, counted vmcnt(2), raw barriers —
//          loads stay in flight across barriers; 1 barrier/chunk).
// Phase 2: exact softmax (shuffles + cross-wave LDS reduce), attn f32 written
//          from normalized registers.
// Phase 3: per 64-col stile: P -> Pst LDS (padded 144-B rows); V fragments
//          loaded as contiguous 1-KB wave reads from fragment-packed Vf,
//          prefetched before the (lgkm-only) barriers so vmem stays in flight.
// ---------------------------------------------------------------------------
__global__ __launch_bounds__(512, 2) void attn_kernel(
    const bf16* __restrict__ Q, const bf16* __restrict__ Km,
    const bf16* __restrict__ Vf, float* __restrict__ attn,
    bf16* __restrict__ O) {
  __shared__ __align__(16) bf16 Kring[3][64][128];  // 48 KB ring
  __shared__ float red[512];                        // 2 KB
  __shared__ __align__(16) bf16 Pst[32][72];        // 4.6 KB, 144-B rows

  const int b = blockIdx.x & 7;
  const int q0 = (blockIdx.x >> 3) << 5;
  const int tid = threadIdx.x, lane = tid & 63, w = tid >> 6;
  const int rg = w >> 2, cgi = w & 3;
  const int quad = lane >> 4, l15 = lane & 15;
  const float scale = 0.044194173824159216f;  // 1/sqrt(512)

  const bf16* Kb = Km + (size_t)b * 2048 * 512;

  // Q fragments direct from global (one-time; 16 x 16B per lane)
  bf16x8v a[16];
  {
    const bf16* qrow = Q + ((size_t)b * 2048 + q0 + rg * 16 + l15) * 512 + quad * 8;
#pragma unroll
    for (int kk = 0; kk < 16; kk++) a[kk] = *(const bf16x8v*)(qrow + kk * 32);
  }

  f32x4v acc[32];
#pragma unroll
  for (int st = 0; st < 32; st++) acc[st] = (f32x4v){0.f, 0.f, 0.f, 0.f};

  // ---- phase 1: S = Q K^T ----
  stage_k(Kb, (char*)Kring, 0, 0, w, lane);
  stage_k(Kb, (char*)Kring, 1, 1, w, lane);
  WAIT_VMCNT_0;  // drain Q loads + prologue stages (removes issue-order deps)
  BARRIER;

#pragma unroll
  for (int c = 0; c < 128; ++c) {
    WAIT_VMCNT_2;   // my chunk-c stage complete (chunk c+1 may stay in flight)
    WAIT_LGKM_0;    // my prior ds_reads retired (slot about to be re-staged)
    BARRIER;        // publish chunk c; license re-staging slot (c+2)%3
    const int cn = (c + 2 > 127) ? 127 : (c + 2);  // clamped re-stage: uniform vmcnt
    stage_k(Kb, (char*)Kring, cn, (c + 2) % 3, w, lane);
    const int stile = c & 31, dc = c >> 5;  // dc-major: acc chains are only 4 deep
    const char* kb = (const char*)Kring + (c % 3) * 16384 + (cgi * 16 + l15) * 256;
    f32x4v t = acc[stile];
#pragma unroll
    for (int kk = 0; kk < 4; kk++) {
      bf16x8v bfr = *(const bf16x8v*)(kb + (((kk * 4 + quad) ^ (l15 & 7)) << 4));
      t = MFMA(a[dc * 4 + kk], bfr, t);
    }
    acc[stile] = t;
  }
  WAIT_VMCNT_0;  // drain stray clamped stages (write dead Kring slots only)
  BARRIER;

#pragma unroll
  for (int st = 0; st < 32; st++) acc[st] = acc[st] * scale;

  // ---- phase 2: softmax stats (l15 shuffles + cross-wave LDS reduce) ----
  float m[4], l[4];
#pragma unroll
  for (int r = 0; r < 4; r++) m[r] = -1e30f;
#pragma unroll
  for (int st = 0; st < 32; st++)
#pragma unroll
    for (int r = 0; r < 4; r++) m[r] = fmaxf(m[r], acc[st][r]);
#pragma unroll
  for (int off = 1; off < 16; off <<= 1)
#pragma unroll
    for (int r = 0; r < 4; r++) m[r] = fmaxf(m[r], __shfl_xor(m[r], off, 64));
  if (l15 == 0)
#pragma unroll
    for (int r = 0; r < 4; r++) red[rg * 64 + cgi * 16 + quad * 4 + r] = m[r];
  __syncthreads();
#pragma unroll
  for (int r = 0; r < 4; r++) {
    int row = rg * 64 + quad * 4 + r;
    float mm = red[row];
    for (int ww = 1; ww < 4; ww++) mm = fmaxf(mm, red[row + ww * 16]);
    m[r] = mm;
  }
#pragma unroll
  for (int r = 0; r < 4; r++) l[r] = 0.f;
#pragma unroll
  for (int st = 0; st < 32; st++)
#pragma unroll
    for (int r = 0; r < 4; r++) {
      float p = __expf(acc[st][r] - m[r]);
      acc[st][r] = p;
      l[r] += p;
    }
#pragma unroll
  for (int off = 1; off < 16; off <<= 1)
#pragma unroll
    for (int r = 0; r < 4; r++) l[r] += __shfl_xor(l[r], off, 64);
  if (l15 == 0)
#pragma unroll
    for (int r = 0; r < 4; r++) red[256 + rg * 64 + cgi * 16 + quad * 4 + r] = l[r];
  __syncthreads();
#pragma unroll
  for (int r = 0; r < 4; r++) {
    int row = 256 + rg * 64 + quad * 4 + r;
    float s_ = 0.f;
    for (int ww = 0; ww < 4; ww++) s_ += red[row + ww * 16];
    l[r] = 1.0f / s_;
  }

  // normalize in registers and write attn (f32) directly
#pragma unroll
  for (int st = 0; st < 32; st++) {
#pragma unroll
    for (int r = 0; r < 4; r++) {
      float p = acc[st][r] * l[r];
      acc[st][r] = p;
      attn[((size_t)(b * 2048) + q0 + rg * 16 + quad * 4 + r) * 2048 + st * 64 +
           cgi * 16 + l15] = p;
    }
  }

  // ---- phase 3: O = P V, per 64-col stile; V fragment-packed from global ----
  f32x4v acc2[2][4];
#pragma unroll
  for (int hg = 0; hg < 2; hg++)
#pragma unroll
    for (int j = 0; j < 4; j++) acc2[hg][j] = (f32x4v){0.f, 0.f, 0.f, 0.f};
  const bf16* Vfb = Vf + (size_t)b * (1 << 20);  // 2 MB/batch, frag-packed
  const int w4 = w * 4;
  const int lane8 = lane * 8;

#pragma unroll
  for (int st = 0; st < 32; st++) {
    // prefetch this stile's 8 V fragments (contiguous 1 KB wave loads);
    // lgkm-only barriers below keep these vmem loads in flight.
    bf16x8v vf[2][4];
#pragma unroll
    for (int ss = 0; ss < 2; ss++)
#pragma unroll
      for (int j = 0; j < 4; j++)
        vf[ss][j] = *(const bf16x8v*)(Vfb + ((size_t)(w4 + j) * 64 + st * 2 + ss) * 512 + lane8);
    WAIT_LGKM_0;  // prior stile's Pst reads retired
    BARRIER;
#pragma unroll
    for (int r = 0; r < 4; r++)
      Pst[rg * 16 + quad * 4 + r][cgi * 16 + l15] = (bf16)acc[st][r];
    WAIT_LGKM_0;  // my Pst writes done
    BARRIER;      // Pst published
    const char* pb = (const char*)Pst;
#pragma unroll
    for (int ss = 0; ss < 2; ss++) {
      bf16x8v a0 = *(const bf16x8v*)(pb + l15 * 144 + ss * 64 + quad * 16);
      bf16x8v a1 = *(const bf16x8v*)(pb + (16 + l15) * 144 + ss * 64 + quad * 16);
#pragma unroll
      for (int j = 0; j < 4; j++) {
        acc2[0][j] = MFMA(a0, vf[ss][j], acc2[0][j]);
        acc2[1][j] = MFMA(a1, vf[ss][j], acc2[1][j]);
      }
    }
  }

#pragma unroll
  for (int hg = 0; hg < 2; hg++)
#pragma unroll
    for (int j = 0; j < 4; j++) {
      int col = w * 64 + j * 16 + l15;
#pragma unroll
      for (int r = 0; r < 4; r++) {
        int row = q0 + hg * 16 + quad * 4 + r;
        O[((size_t)b * 2048 + row) * 512 + col] = (bf16)acc2[hg][j][r];
      }
    }
}

// ---------------------------------------------------------------------------
// K3: out-projection + bias + residual + LayerNorm, fused. Output f32.
// ---------------------------------------------------------------------------
__global__ __launch_bounds__(256) void proj_ln(
    const bf16* __restrict__ O, const bf16* __restrict__ WTp,
    const float* __restrict__ bp, const float* __restrict__ X,
    const float* __restrict__ gamma, const float* __restrict__ beta,
    float* __restrict__ Y) {
  __shared__ bf16 Bs[512][40];
  const int m0 = blockIdx.x * 64;
  const int tid = threadIdx.x, lane = tid & 63, w = tid >> 6;
  const int quad = lane >> 4, l15 = lane & 15;

  f32x4v acc[32];
#pragma unroll
  for (int j = 0; j < 32; j++) acc[j] = (f32x4v){0.f, 0.f, 0.f, 0.f};

  const int srow = tid >> 2, scol = (tid & 3) * 8;
  for (int kt = 0; kt < 16; ++kt) {
    const int k0 = kt * 32;
#pragma unroll
    for (int it = 0; it < 8; ++it) {
      int r = it * 64 + srow;
      *(bf16x8v*)&Bs[r][scol] = *(const bf16x8v*)&WTp[(size_t)r * 512 + k0 + scol];
    }
    __syncthreads();
    bf16x8v a_ = *(const bf16x8v*)&O[(size_t)(m0 + w * 16 + l15) * 512 + k0 + quad * 8];
#pragma unroll
    for (int j = 0; j < 32; j++) {
      bf16x8v b_ = *(const bf16x8v*)&Bs[j * 16 + l15][quad * 8];
      acc[j] = MFMA(a_, b_, acc[j]);
    }
    __syncthreads();
  }

#pragma unroll
  for (int j = 0; j < 32; j++) {
    int col = j * 16 + l15;
    float bpv = bp[col];
#pragma unroll
    for (int r = 0; r < 4; r++) {
      size_t row = m0 + w * 16 + quad * 4 + r;
      acc[j][r] = acc[j][r] + bpv + X[row * 512 + col];
    }
  }
  float s1[4] = {0.f, 0.f, 0.f, 0.f}, s2[4] = {0.f, 0.f, 0.f, 0.f};
#pragma unroll
  for (int j = 0; j < 32; j++)
#pragma unroll
    for (int r = 0; r < 4; r++) {
      s1[r] += acc[j][r];
      s2[r] += acc[j][r] * acc[j][r];
    }
#pragma unroll
  for (int off = 1; off < 16; off <<= 1)
#pragma unroll
    for (int r = 0; r < 4; r++) {
      s1[r] += __shfl_xor(s1[r], off, 64);
      s2[r] += __shfl_xor(s2[r], off, 64);
    }
  float mu[4], rs[4];
#pragma unroll
  for (int r = 0; r < 4; r++) {
    mu[r] = s1[r] * (1.0f / 512.0f);
    float var = s2[r] * (1.0f / 512.0f) - mu[r] * mu[r];
    rs[r] = rsqrtf(var + 1e-5f);
  }
#pragma unroll
  for (int j = 0; j < 32; j++) {
    int col = j * 16 + l15;
    float g = gamma[col], be = beta[col];
#pragma unroll
    for (int r = 0; r < 4; r++) {
      int row = m0 + w * 16 + quad * 4 + r;
      Y[(size_t)row * 512 + col] = (acc[j][r] - mu[r]) * rs[r] * g + be;
    }
  }
}

// ---------------------------------------------------------------------------
extern "C" void kernel_launch(void* const* d_in, const int* in_sizes, int n_in,
                              void* d_out, int out_size, void* d_ws, size_t ws_size,
                              hipStream_t stream) {
  const float* x = (const float*)d_in[0];
  const float* Wq = (const float*)d_in[1];
  const float* bq = (const float*)d_in[2];
  const float* Wk = (const float*)d_in[3];
  const float* bk = (const float*)d_in[4];
  const float* Wv = (const float*)d_in[5];
  const float* bv = (const float*)d_in[6];
  const float* Wp = (const float*)d_in[7];
  const float* bp = (const float*)d_in[8];
  const float* gamma = (const float*)d_in[9];
  const float* beta = (const float*)d_in[10];

  char* ws = (char*)d_ws;
  bf16* WT = (bf16*)ws;                                      // 2 MB
  size_t off = 4ull * 512 * 512 * 2;
  bf16* Qd = (bf16*)(ws + off); off += 16384ull * 512 * 2;   // 16 MB
  bf16* Kd = (bf16*)(ws + off); off += 16384ull * 512 * 2;   // 16 MB
  bf16* Vfd = (bf16*)(ws + off); off += 16384ull * 512 * 2;  // 16 MB (frag-packed)

  float* Y = (float*)d_out;                     // f32 [8][2048][512]
  float* attn = Y + 8ull * 2048 * 512;          // f32 [8][2048][2048]
  bf16* Xb = (bf16*)d_out;  // bf16 X parked in Y region (consumed by qkv_gemm)
  bf16* Od = Qd;            // O overwrites Q in place (row-disjoint per block)

  hipLaunchKernelGGL(conv_weights, dim3(16, 16, 4), dim3(32, 32), 0, stream,
                     Wq, Wk, Wv, Wp, WT);
  hipLaunchKernelGGL(conv_x, dim3(4096), dim3(256), 0, stream, x, Xb);
  hipLaunchKernelGGL(qkv_gemm, dim3(4, 128, 3), dim3(256), 0, stream,
                     Xb, WT, bq, bk, bv, Qd, Kd, Vfd);
  hipLaunchKernelGGL(attn_kernel, dim3(512), dim3(512), 0, stream,
                     Qd, Kd, Vfd, attn, Od);
  hipLaunchKernelGGL(proj_ln, dim3(256), dim3(256), 0, stream,
                     Od, WT + 3ull * 512 * 512, bp, x, gamma, beta, Y);
}